// Round 14
// baseline (225.121 us; speedup 1.0000x reference)
//
#include <hip/hip_runtime.h>
#include <hip/hip_bf16.h>
#include <stdint.h>

#define B_ 2
#define S_ 2048
#define D_ 1024
#define H_ 16
#define HD_ 64
#define SCALE_ 0.125f
#define SC2_ 0.18033688011112042f   // SCALE * log2(e)

typedef __attribute__((ext_vector_type(8))) short bfx8;
typedef __attribute__((ext_vector_type(4))) float f32x4;

#define VWAIT(n) asm volatile("s_waitcnt vmcnt(" #n ")" ::: "memory")

// async global->LDS, 16B per lane; LDS dest = wave-uniform base + lane*16
__device__ __forceinline__ void gld_lds16(const void* g, void* l) {
    __builtin_amdgcn_global_load_lds(
        (const __attribute__((address_space(1))) void*)g,
        (__attribute__((address_space(3))) void*)l, 16, 0, 0);
}

// ---------------------------------------------------------------------------
// merged prep: blocks [0,12288) cast q/k/v f32->bf16; [12288,16384) transpose+
// cast the four weight matrices W[K][N] -> Wt[N][K]. One launch instead of two.
__global__ __launch_bounds__(256) void prep(
    const float* __restrict__ a, const float* __restrict__ b, const float* __restrict__ c,
    __hip_bfloat16* __restrict__ oa, __hip_bfloat16* __restrict__ ob, __hip_bfloat16* __restrict__ oc,
    const float* __restrict__ w0, const float* __restrict__ w1,
    const float* __restrict__ w2, const float* __restrict__ w3,
    __hip_bfloat16* __restrict__ o0, __hip_bfloat16* __restrict__ o1,
    __hip_bfloat16* __restrict__ o2, __hip_bfloat16* __restrict__ o3)
{
    __shared__ float t[32][33];
    const int bid = blockIdx.x;
    if (bid < 12288) {
        const int which = bid >> 12;             // /4096
        const int xb = bid & 4095;
        const float* src = which == 0 ? a : which == 1 ? b : c;
        __hip_bfloat16* dst = which == 0 ? oa : which == 1 ? ob : oc;
        const size_t i = ((size_t)xb * 256 + threadIdx.x) * 4;
        float4 v = *(const float4*)(src + i);
        ushort4 u;
        __hip_bfloat16 tt;
        tt = __float2bfloat16(v.x); u.x = *(unsigned short*)&tt;
        tt = __float2bfloat16(v.y); u.y = *(unsigned short*)&tt;
        tt = __float2bfloat16(v.z); u.z = *(unsigned short*)&tt;
        tt = __float2bfloat16(v.w); u.w = *(unsigned short*)&tt;
        *(ushort4*)(dst + i) = u;
    } else {
        const int tb = bid - 12288;
        const int z = tb >> 10;                  // /1024 -> matrix 0..3
        const int rem = tb & 1023;
        const int bx = (rem & 31) * 32, by = (rem >> 5) * 32;
        const float* W = z == 0 ? w0 : z == 1 ? w1 : z == 2 ? w2 : w3;
        __hip_bfloat16* Wt = z == 0 ? o0 : z == 1 ? o1 : z == 2 ? o2 : o3;
        const int x = threadIdx.x & 31, y = threadIdx.x >> 5;   // 32 x 8
#pragma unroll
        for (int i = 0; i < 32; i += 8)
            t[y + i][x] = W[(size_t)(by + y + i) * 1024 + bx + x];
        __syncthreads();
#pragma unroll
        for (int i = 0; i < 32; i += 8)
            Wt[(size_t)(bx + y + i) * 1024 + by + x] = __float2bfloat16(t[x][y + i]);
    }
}

// transpose V projection: [B,H,S,64] -> [B,H,64,S]
__global__ __launch_bounds__(256) void transpose_v(
    const __hip_bfloat16* __restrict__ vn,   // [B,H,S,64]
    __hip_bfloat16* __restrict__ vtb)        // [B,H,64,S]
{
    __shared__ unsigned int t[64][65];
    const int bh = blockIdx.y;               // 0..31
    const int st = blockIdx.x;               // s-tile 0..31
    const int tid = threadIdx.x, lane = tid & 63, w = tid >> 6;
    {
        const int sl = tid >> 2, c0 = (tid & 3) * 16;
        const ushort4* src = (const ushort4*)(vn + ((size_t)bh * S_ + st * 64 + sl) * 64 + c0);
        ushort4 a = src[0], b = src[1], c = src[2], d = src[3];
        unsigned short vals[16] = {a.x,a.y,a.z,a.w,b.x,b.y,b.z,b.w,
                                   c.x,c.y,c.z,c.w,d.x,d.y,d.z,d.w};
#pragma unroll
        for (int j = 0; j < 16; ++j) t[sl][c0 + j] = vals[j];
    }
    __syncthreads();
    const int sl2 = (lane & 31) * 2;         // 0..62 (s pair within tile)
    const int dh  = (lane >> 5) * 8;         // 0 or 8 (d-half within wave's 16)
#pragma unroll
    for (int j = 0; j < 8; ++j) {
        const int d = w * 16 + dh + j;
        const unsigned int lo = t[sl2][d], hi = t[sl2 + 1][d];
        const unsigned int pk = (lo & 0xFFFFu) | (hi << 16);
        *(unsigned int*)(vtb + ((size_t)bh * HD_ + d) * S_ + st * 64 + sl2) = pk;
    }
}

// ---------------------------------------------------------------------------
// bf16 GEMM body (128x128 tile): proven 2-buffer __syncthreads structure.
__device__ __forceinline__ void gemm_body(
    const __hip_bfloat16* __restrict__ A,
    const __hip_bfloat16* __restrict__ Bt,
    const float* __restrict__ bias,
    void* __restrict__ Cout, int mode,
    __hip_bfloat16 (*As)[128 * 32], __hip_bfloat16 (*Bs)[128 * 32],
    int bm, int bn)
{
    constexpr int K = 1024, N = 1024;
    const int tid = threadIdx.x;
    const int wid = tid >> 6, lane = tid & 63;
    const int wm = (wid >> 1) * 64, wn = (wid & 1) * 64;

    f32x4 acc[4][4] = {};

    const int srow = lane >> 2;          // 0..15 (row within 16-row chunk)
    const int scol = (lane & 3) * 8;     // elem col within 32-elem row

    auto stage = [&](int kt, int buf) {
#pragma unroll
        for (int i = 0; i < 2; ++i) {
            const int rb = wid * 32 + i * 16;
            gld_lds16(A  + (size_t)(bm + rb + srow) * K + kt * 32 + scol, (char*)As[buf] + rb * 64);
            gld_lds16(Bt + (size_t)(bn + rb + srow) * K + kt * 32 + scol, (char*)Bs[buf] + rb * 64);
        }
    };

    stage(0, 0);
    __syncthreads();

    for (int kt = 0; kt < K / 32; ++kt) {
        const int cur = kt & 1;
        if (kt < K / 32 - 1) stage(kt + 1, cur ^ 1);
        bfx8 af[4], bf[4];
#pragma unroll
        for (int m = 0; m < 4; ++m)
            af[m] = *(const bfx8*)((const char*)As[cur] + (wm + m * 16 + (lane & 15)) * 64 + (lane >> 4) * 16);
#pragma unroll
        for (int n = 0; n < 4; ++n)
            bf[n] = *(const bfx8*)((const char*)Bs[cur] + (wn + n * 16 + (lane & 15)) * 64 + (lane >> 4) * 16);
        __builtin_amdgcn_s_setprio(1);
#pragma unroll
        for (int m = 0; m < 4; ++m)
#pragma unroll
            for (int n = 0; n < 4; ++n)
                acc[m][n] = __builtin_amdgcn_mfma_f32_16x16x32_bf16(af[m], bf[n], acc[m][n], 0, 0, 0);
        __builtin_amdgcn_s_setprio(0);
        __syncthreads();
    }

#pragma unroll
    for (int m = 0; m < 4; ++m) {
        const int row0 = bm + wm + m * 16 + ((lane >> 4) << 2);
#pragma unroll
        for (int n = 0; n < 4; ++n) {
            const int col = bn + wn + n * 16 + (lane & 15);
            const float bv = bias[col];
#pragma unroll
            for (int r = 0; r < 4; ++r) {
                const int i = row0 + r;
                const float v = acc[m][n][r] + bv;
                if (mode == 2) {
                    ((float*)Cout)[(size_t)i * N + col] = v;
                } else {
                    const int b = i >> 11, s = i & 2047, h = col >> 6, d = col & 63;
                    ((__hip_bfloat16*)Cout)[(((size_t)b * H_ + h) * S_ + s) * HD_ + d] = __float2bfloat16(v);
                }
            }
        }
    }
}

// fused Q/K/V projections (3 blocks/CU)
__global__ __launch_bounds__(256, 3) void gemm_qkv(
    const __hip_bfloat16* __restrict__ xq, const __hip_bfloat16* __restrict__ xk,
    const __hip_bfloat16* __restrict__ xv,
    const __hip_bfloat16* __restrict__ Wqt, const __hip_bfloat16* __restrict__ Wkt,
    const __hip_bfloat16* __restrict__ Wvt,
    const float* __restrict__ bq, const float* __restrict__ bk, const float* __restrict__ bv,
    __hip_bfloat16* __restrict__ qb, __hip_bfloat16* __restrict__ kbuf,
    __hip_bfloat16* __restrict__ vnb)
{
    __shared__ __align__(16) __hip_bfloat16 As[2][128 * 32];
    __shared__ __align__(16) __hip_bfloat16 Bs[2][128 * 32];
    const int z = blockIdx.z;
    const __hip_bfloat16* A  = z == 0 ? xq : z == 1 ? xk : xv;
    const __hip_bfloat16* Bt = z == 0 ? Wqt : z == 1 ? Wkt : Wvt;
    const float* bias        = z == 0 ? bq : z == 1 ? bk : bv;
    void* out                = z == 0 ? (void*)qb : z == 1 ? (void*)kbuf : (void*)vnb;
    gemm_body(A, Bt, bias, out, 0, As, Bs, blockIdx.x * 128, blockIdx.y * 128);
}

// output projection: BM=128, BN=64 tile -> 512 blocks = 2/CU
__global__ __launch_bounds__(256, 2) void gemm_wo(
    const __hip_bfloat16* __restrict__ A, const __hip_bfloat16* __restrict__ Bt,
    const float* __restrict__ bias, float* __restrict__ Cout)
{
    constexpr int K = 1024, N = 1024;
    __shared__ __align__(16) __hip_bfloat16 As[2][128 * 32];
    __shared__ __align__(16) __hip_bfloat16 Bs[2][64 * 32];
    const int tid = threadIdx.x;
    const int wid = tid >> 6, lane = tid & 63;
    const int wm = (wid >> 1) * 64, wn = (wid & 1) * 32;
    const int bm = blockIdx.x * 128, bn = blockIdx.y * 64;

    f32x4 acc[4][2] = {};

    const int srow = lane >> 2;
    const int scol = (lane & 3) * 8;

    auto stage = [&](int kt, int buf) {
#pragma unroll
        for (int i = 0; i < 2; ++i) {
            const int rb = wid * 32 + i * 16;
            gld_lds16(A + (size_t)(bm + rb + srow) * K + kt * 32 + scol, (char*)As[buf] + rb * 64);
        }
        const int rbB = wid * 16;
        gld_lds16(Bt + (size_t)(bn + rbB + srow) * K + kt * 32 + scol, (char*)Bs[buf] + rbB * 64);
    };

    stage(0, 0);
    __syncthreads();

    for (int kt = 0; kt < K / 32; ++kt) {
        const int cur = kt & 1;
        if (kt < K / 32 - 1) stage(kt + 1, cur ^ 1);
        bfx8 af[4], bf[2];
#pragma unroll
        for (int m = 0; m < 4; ++m)
            af[m] = *(const bfx8*)((const char*)As[cur] + (wm + m * 16 + (lane & 15)) * 64 + (lane >> 4) * 16);
#pragma unroll
        for (int n = 0; n < 2; ++n)
            bf[n] = *(const bfx8*)((const char*)Bs[cur] + (wn + n * 16 + (lane & 15)) * 64 + (lane >> 4) * 16);
        __builtin_amdgcn_s_setprio(1);
#pragma unroll
        for (int m = 0; m < 4; ++m)
#pragma unroll
            for (int n = 0; n < 2; ++n)
                acc[m][n] = __builtin_amdgcn_mfma_f32_16x16x32_bf16(af[m], bf[n], acc[m][n], 0, 0, 0);
        __builtin_amdgcn_s_setprio(0);
        __syncthreads();
    }

#pragma unroll
    for (int m = 0; m < 4; ++m) {
        const int row0 = bm + wm + m * 16 + ((lane >> 4) << 2);
#pragma unroll
        for (int n = 0; n < 2; ++n) {
            const int col = bn + wn + n * 16 + (lane & 15);
            const float bv = bias[col];
#pragma unroll
            for (int r = 0; r < 4; ++r)
                Cout[(size_t)(row0 + r) * N + col] = acc[m][n][r] + bv;
        }
    }
}

// ---------------------------------------------------------------------------
// Fused attention: each block owns TWO adjacent q-tiles (A,B) of one head.
// pass1 computes BOTH denominators in one K-sweep — the bfv K-fragments are
// shared, B adds only 8 MFMA + exp per tile (rides the same ds_reads), so
// ~half of all GPU-wide pass-1 (no-store) time is eliminated and the store
// engine stays busier. pass2 runs twice (A then B), unchanged structure:
// swapped QK^T, packed P-writes, nt f32x4 attnw stores riding via vmcnt(4).
// 512 blocks (2/CU resident; R4/R5 showed 2-vs-4 blocks/CU is neutral here).
__global__ __launch_bounds__(256, 4) void attn_fused(
    const __hip_bfloat16* __restrict__ qb,   // [B,H,S,64]
    const __hip_bfloat16* __restrict__ kb,   // [B,H,S,64]
    const __hip_bfloat16* __restrict__ vt,   // [B,H,64,S]
    float* __restrict__ attnw,               // [B,H,S,S]
    __hip_bfloat16* __restrict__ aout)       // [B,S,H*64]
{
    __shared__ __align__(16) char lds_[40960];
    char* const ps_ = lds_ + 32768;          // 64 rows x 128B

    // XCD-chunked swizzle: 512 blocks; each XCD gets 64 contiguous lin = 4 heads
    const int wg  = blockIdx.x;              // 0..511
    const int lin = (wg & 7) * 64 + (wg >> 3);
    const int bh  = lin >> 4;                // b*16+h
    const int jj  = lin & 15;                // q-tile pair 0..15
    const int qtA = jj * 2, qtB = jj * 2 + 1;

    const int tid = threadIdx.x, wid = tid >> 6, lane = tid & 63;

    const char* kh = (const char*)(kb + (size_t)bh * S_ * HD_);   // head base
    const char* vh = (const char*)(vt + (size_t)bh * HD_ * S_);

    // Q fragments for both q-tiles: rows qt*64 + wid*16 + (lane&15)
    bfx8 qfA[2], qfB[2];
#pragma unroll
    for (int kx = 0; kx < 2; ++kx) {
        qfA[kx] = *(const bfx8*)(qb + ((size_t)bh * S_ + qtA * 64 + wid * 16 + (lane & 15)) * HD_
                                  + kx * 32 + (lane >> 4) * 8);
        qfB[kx] = *(const bfx8*)(qb + ((size_t)bh * S_ + qtB * 64 + wid * 16 + (lane & 15)) * HD_
                                  + kx * 32 + (lane >> 4) * 8);
    }

    const int sr = lane >> 3;   // row within 8-row staging chunk
    const int sc = lane & 7;    // 16B unit within 128B row

    auto stage_k = [&](int kt, char* dst) {
#pragma unroll
        for (int i = 0; i < 2; ++i) {
            const int rb = wid * 16 + i * 8;
            const int row = rb + sr;
            const int colb = (sc * 16) ^ ((row & 7) << 4);
            gld_lds16(kh + (size_t)(kt * 64 + row) * 128 + colb, dst + rb * 128);
        }
    };
    auto stage_v = [&](int kt, char* dst) {
#pragma unroll
        for (int i = 0; i < 2; ++i) {
            const int rb = wid * 16 + i * 8;
            const int row = rb + sr;
            const int colb = (sc * 16) ^ ((row & 7) << 4);
            gld_lds16(vh + ((size_t)row * S_ + kt * 64) * 2 + colb, dst + rb * 128);
        }
    };

    // ------- pass 1: BOTH denominators, K ring-4, prefetch depth 2 ----------
    float lsumA = 0.f, lsumB = 0.f;
    stage_k(0, lds_);
    stage_k(1, lds_ + 8192);
    for (int kt = 0; kt < 32; ++kt) {
        if (kt < 30) {
            stage_k(kt + 2, lds_ + ((kt + 2) & 3) * 8192);
            VWAIT(4);                       // loads(kt) retired; kt+1,kt+2 ride
        } else if (kt == 30) { VWAIT(2); } else { VWAIT(0); }
        __builtin_amdgcn_sched_barrier(0);
        __builtin_amdgcn_s_barrier();

        const char* kbase = lds_ + (kt & 3) * 8192;
        f32x4 cA[4] = {}, cB[4] = {};
#pragma unroll
        for (int kx = 0; kx < 2; ++kx) {
            bfx8 bfv[4];
#pragma unroll
            for (int cf = 0; cf < 4; ++cf) {
                const int row = cf * 16 + (lane & 15);
                bfv[cf] = *(const bfx8*)(kbase + row * 128
                                          + ((kx * 64 + (lane >> 4) * 16) ^ ((row & 7) << 4)));
            }
            __builtin_amdgcn_s_setprio(1);
#pragma unroll
            for (int cf = 0; cf < 4; ++cf)
                cA[cf] = __builtin_amdgcn_mfma_f32_16x16x32_bf16(bfv[cf], qfA[kx], cA[cf], 0, 0, 0);
#pragma unroll
            for (int cf = 0; cf < 4; ++cf)
                cB[cf] = __builtin_amdgcn_mfma_f32_16x16x32_bf16(bfv[cf], qfB[kx], cB[cf], 0, 0, 0);
            __builtin_amdgcn_s_setprio(0);
        }
#pragma unroll
        for (int cf = 0; cf < 4; ++cf) {
            lsumA += exp2f(cA[cf][0] * SC2_) + exp2f(cA[cf][1] * SC2_)
                   + exp2f(cA[cf][2] * SC2_) + exp2f(cA[cf][3] * SC2_);
            lsumB += exp2f(cB[cf][0] * SC2_) + exp2f(cB[cf][1] * SC2_)
                   + exp2f(cB[cf][2] * SC2_) + exp2f(cB[cf][3] * SC2_);
        }
    }
    float llogA, llogB;
    {
        float s = lsumA;
        s += __shfl_xor(s, 16); s += __shfl_xor(s, 32);
        llogA = -__log2f(s);
        float u = lsumB;
        u += __shfl_xor(u, 16); u += __shfl_xor(u, 32);
        llogB = -__log2f(u);
    }

    // ------- pass 2: weights + PV, run for half A then half B ---------------
#pragma unroll
    for (int half = 0; half < 2; ++half) {
        const int qt = half == 0 ? qtA : qtB;
        const float llog = half == 0 ? llogA : llogB;
        const bfx8 qh0 = half == 0 ? qfA[0] : qfB[0];
        const bfx8 qh1 = half == 0 ? qfA[1] : qfB[1];
        const int qrow0 = qt * 64 + wid * 16;

        f32x4 o[4] = {};
        stage_k(0, lds_);
        stage_v(0, lds_ + 16384);
        VWAIT(0);
        __builtin_amdgcn_s_barrier();
        for (int kt = 0; kt < 32; ++kt) {
            const int cur = kt & 1;
            const char* ksb = lds_ + cur * 8192;
            const char* vsb = lds_ + 16384 + cur * 8192;

            if (kt < 31) {
                stage_k(kt + 1, lds_ + (cur ^ 1) * 8192);
                stage_v(kt + 1, lds_ + 16384 + (cur ^ 1) * 8192);
            }

            // swapped QK^T: c[cf][r] = s[k=cf*16+(lane>>4)*4+r][q=lane&15]
            f32x4 c[4] = {};
#pragma unroll
            for (int kx = 0; kx < 2; ++kx) {
                const bfx8 qf = kx == 0 ? qh0 : qh1;
                bfx8 bfv[4];
#pragma unroll
                for (int cf = 0; cf < 4; ++cf) {
                    const int row = cf * 16 + (lane & 15);
                    bfv[cf] = *(const bfx8*)(ksb + row * 128
                                              + ((kx * 64 + (lane >> 4) * 16) ^ ((row & 7) << 4)));
                }
                __builtin_amdgcn_s_setprio(1);
#pragma unroll
                for (int cf = 0; cf < 4; ++cf)
                    c[cf] = __builtin_amdgcn_mfma_f32_16x16x32_bf16(bfv[cf], qf, c[cf], 0, 0, 0);
                __builtin_amdgcn_s_setprio(0);
            }

            // normalized bf16 weights -> swizzled LDS, 4 packed b64 writes/lane
            {
                const int q = lane & 15;
                char* const prow_base = ps_ + (wid * 16 + q) * 128;
                const int swz = (q & 7) << 4;
#pragma unroll
                for (int cf = 0; cf < 4; ++cf) {
                    const int k0b = (cf * 16 + (lane >> 4) * 4) * 2;
                    ushort4 pk;
                    __hip_bfloat16 bb;
                    bb = __float2bfloat16(exp2f(fmaf(c[cf][0], SC2_, llog))); pk.x = *(unsigned short*)&bb;
                    bb = __float2bfloat16(exp2f(fmaf(c[cf][1], SC2_, llog))); pk.y = *(unsigned short*)&bb;
                    bb = __float2bfloat16(exp2f(fmaf(c[cf][2], SC2_, llog))); pk.z = *(unsigned short*)&bb;
                    bb = __float2bfloat16(exp2f(fmaf(c[cf][3], SC2_, llog))); pk.w = *(unsigned short*)&bb;
                    *(ushort4*)(prow_base + (k0b ^ swz)) = pk;
                }
            }

            // coalesced attnw stores: 4 nt f32x4 stores/wave (full 256B lines)
#pragma unroll
            for (int rr = 0; rr < 4; ++rr) {
                const int p = wid * 16 + rr * 4 + (lane >> 4);
                const uint2 u = *(const uint2*)(ps_ + p * 128
                                                + (((lane & 15) * 8) ^ ((p & 7) << 4)));
                f32x4 f;
                f[0] = __uint_as_float(u.x << 16);
                f[1] = __uint_as_float(u.x & 0xFFFF0000u);
                f[2] = __uint_as_float(u.y << 16);
                f[3] = __uint_as_float(u.y & 0xFFFF0000u);
                __builtin_nontemporal_store(f,
                    (f32x4*)(attnw + ((size_t)bh * S_ + qt * 64 + p) * S_ + kt * 64 + (lane & 15) * 4));
            }

            // O += P @ V   (P rows are wave-local: no barrier needed)
#pragma unroll
            for (int kx = 0; kx < 2; ++kx) {
                bfx8 pf, vf[4];
                {
                    const int prow = wid * 16 + (lane & 15);
                    pf = *(const bfx8*)(ps_ + prow * 128
                                         + ((kx * 64 + (lane >> 4) * 16) ^ ((prow & 7) << 4)));
                }
#pragma unroll
                for (int df = 0; df < 4; ++df) {
                    const int vrow = df * 16 + (lane & 15);
                    vf[df] = *(const bfx8*)(vsb + vrow * 128
                                             + ((kx * 64 + (lane >> 4) * 16) ^ ((vrow & 7) << 4)));
                }
                __builtin_amdgcn_s_setprio(1);
#pragma unroll
                for (int df = 0; df < 4; ++df)
                    o[df] = __builtin_amdgcn_mfma_f32_16x16x32_bf16(pf, vf[df], o[df], 0, 0, 0);
                __builtin_amdgcn_s_setprio(0);
            }

            if (kt < 31) {
                VWAIT(4);                          // stage loads done; stores ride on
                __builtin_amdgcn_sched_barrier(0);
                __builtin_amdgcn_s_barrier();
            }
        }

        // write attention output (bf16) at [B,S,H*64] for the final GEMM
        const int b = bh >> 4, h = bh & 15;
#pragma unroll
        for (int r = 0; r < 4; ++r) {
            const int s = qrow0 + ((lane >> 4) << 2) + r;
#pragma unroll
            for (int df = 0; df < 4; ++df) {
                const int d = df * 16 + (lane & 15);
                aout[((size_t)b * S_ + s) * D_ + h * HD_ + d] = __float2bfloat16(o[df][r]);
            }
        }

        // separate half-A's trailing reads from half-B's tile-0 staging:
        // all waves passed the kt=30 barrier; kt=31 reads buf1 while B's
        // tile0 targets buf0, then the VWAIT(0)+barrier at B's prologue syncs.
    }
}

// ---------------------------------------------------------------------------
extern "C" void kernel_launch(void* const* d_in, const int* in_sizes, int n_in,
                              void* d_out, int out_size, void* d_ws, size_t ws_size,
                              hipStream_t stream)
{
    (void)in_sizes; (void)n_in; (void)out_size; (void)ws_size;
    const float* query = (const float*)d_in[0];
    const float* key_  = (const float*)d_in[1];
    const float* value = (const float*)d_in[2];
    const float* Wq = (const float*)d_in[3];
    const float* bq = (const float*)d_in[4];
    const float* Wk = (const float*)d_in[5];
    const float* bk = (const float*)d_in[6];
    const float* Wv = (const float*)d_in[7];
    const float* bv = (const float*)d_in[8];
    const float* Wo = (const float*)d_in[9];
    const float* bo = (const float*)d_in[10];

    char* ws = (char*)d_ws;
    const size_t MB = 1u << 20;
    __hip_bfloat16* xq   = (__hip_bfloat16*)(ws + 0 * MB);
    __hip_bfloat16* xk   = (__hip_bfloat16*)(ws + 8 * MB);
    __hip_bfloat16* xv   = (__hip_bfloat16*)(ws + 16 * MB);
    __hip_bfloat16* Wqt  = (__hip_bfloat16*)(ws + 24 * MB);
    __hip_bfloat16* Wkt  = (__hip_bfloat16*)(ws + 26 * MB);
    __hip_bfloat16* Wvt  = (__hip_bfloat16*)(ws + 28 * MB);
    __hip_bfloat16* Wot  = (__hip_bfloat16*)(ws + 30 * MB);
    __hip_bfloat16* qb   = (__hip_bfloat16*)(ws + 32 * MB);
    __hip_bfloat16* kbuf = (__hip_bfloat16*)(ws + 40 * MB);
    __hip_bfloat16* vtb  = (__hip_bfloat16*)(ws + 48 * MB);
    // vnb (natural-layout V) aliases aout: vnb is dead after transpose_v,
    // and attn_fused (which writes aout) runs strictly after it.
    __hip_bfloat16* vnb  = (__hip_bfloat16*)(ws + 56 * MB);
    __hip_bfloat16* aout = (__hip_bfloat16*)(ws + 56 * MB);

    float* outp  = (float*)d_out;
    float* attnw = outp + (size_t)B_ * S_ * D_;

    prep<<<dim3(16384), 256, 0, stream>>>(query, key_, value, xq, xk, xv,
                                          Wq, Wk, Wv, Wo, Wqt, Wkt, Wvt, Wot);
    gemm_qkv<<<dim3(32, 8, 3), 256, 0, stream>>>(xq, xk, xv, Wqt, Wkt, Wvt, bq, bk, bv, qb, kbuf, vnb);
    transpose_v<<<dim3(32, 32), 256, 0, stream>>>(vnb, vtb);
    attn_fused<<<dim3(512), 256, 0, stream>>>(qb, kbuf, vtb, attnw, aout);
    gemm_wo<<<dim3(32, 16), 256, 0, stream>>>(aout, Wot, bo, outp);
}

// Round 15
// 201.059 us; speedup vs baseline: 1.1197x; 1.1197x over previous
//
#include <hip/hip_runtime.h>
#include <hip/hip_bf16.h>
#include <stdint.h>

#define B_ 2
#define S_ 2048
#define D_ 1024
#define H_ 16
#define HD_ 64
#define SCALE_ 0.125f
#define SC2_ 0.18033688011112042f   // SCALE * log2(e)

typedef __attribute__((ext_vector_type(8))) short bfx8;
typedef __attribute__((ext_vector_type(4))) float f32x4;

#define VWAIT(n) asm volatile("s_waitcnt vmcnt(" #n ")" ::: "memory")

// async global->LDS, 16B per lane; LDS dest = wave-uniform base + lane*16
__device__ __forceinline__ void gld_lds16(const void* g, void* l) {
    __builtin_amdgcn_global_load_lds(
        (const __attribute__((address_space(1))) void*)g,
        (__attribute__((address_space(3))) void*)l, 16, 0, 0);
}

// ---------------------------------------------------------------------------
// merged prep: blocks [0,12288) cast q/k/v f32->bf16; [12288,16384) transpose+
// cast the four weight matrices W[K][N] -> Wt[N][K]. One launch instead of two.
__global__ __launch_bounds__(256) void prep(
    const float* __restrict__ a, const float* __restrict__ b, const float* __restrict__ c,
    __hip_bfloat16* __restrict__ oa, __hip_bfloat16* __restrict__ ob, __hip_bfloat16* __restrict__ oc,
    const float* __restrict__ w0, const float* __restrict__ w1,
    const float* __restrict__ w2, const float* __restrict__ w3,
    __hip_bfloat16* __restrict__ o0, __hip_bfloat16* __restrict__ o1,
    __hip_bfloat16* __restrict__ o2, __hip_bfloat16* __restrict__ o3)
{
    __shared__ float t[32][33];
    const int bid = blockIdx.x;
    if (bid < 12288) {
        const int which = bid >> 12;             // /4096
        const int xb = bid & 4095;
        const float* src = which == 0 ? a : which == 1 ? b : c;
        __hip_bfloat16* dst = which == 0 ? oa : which == 1 ? ob : oc;
        const size_t i = ((size_t)xb * 256 + threadIdx.x) * 4;
        float4 v = *(const float4*)(src + i);
        ushort4 u;
        __hip_bfloat16 tt;
        tt = __float2bfloat16(v.x); u.x = *(unsigned short*)&tt;
        tt = __float2bfloat16(v.y); u.y = *(unsigned short*)&tt;
        tt = __float2bfloat16(v.z); u.z = *(unsigned short*)&tt;
        tt = __float2bfloat16(v.w); u.w = *(unsigned short*)&tt;
        *(ushort4*)(dst + i) = u;
    } else {
        const int tb = bid - 12288;
        const int z = tb >> 10;                  // /1024 -> matrix 0..3
        const int rem = tb & 1023;
        const int bx = (rem & 31) * 32, by = (rem >> 5) * 32;
        const float* W = z == 0 ? w0 : z == 1 ? w1 : z == 2 ? w2 : w3;
        __hip_bfloat16* Wt = z == 0 ? o0 : z == 1 ? o1 : z == 2 ? o2 : o3;
        const int x = threadIdx.x & 31, y = threadIdx.x >> 5;   // 32 x 8
#pragma unroll
        for (int i = 0; i < 32; i += 8)
            t[y + i][x] = W[(size_t)(by + y + i) * 1024 + bx + x];
        __syncthreads();
#pragma unroll
        for (int i = 0; i < 32; i += 8)
            Wt[(size_t)(bx + y + i) * 1024 + by + x] = __float2bfloat16(t[x][y + i]);
    }
}

// transpose V projection: [B,H,S,64] -> [B,H,64,S]
__global__ __launch_bounds__(256) void transpose_v(
    const __hip_bfloat16* __restrict__ vn,   // [B,H,S,64]
    __hip_bfloat16* __restrict__ vtb)        // [B,H,64,S]
{
    __shared__ unsigned int t[64][65];
    const int bh = blockIdx.y;               // 0..31
    const int st = blockIdx.x;               // s-tile 0..31
    const int tid = threadIdx.x, lane = tid & 63, w = tid >> 6;
    {
        const int sl = tid >> 2, c0 = (tid & 3) * 16;
        const ushort4* src = (const ushort4*)(vn + ((size_t)bh * S_ + st * 64 + sl) * 64 + c0);
        ushort4 a = src[0], b = src[1], c = src[2], d = src[3];
        unsigned short vals[16] = {a.x,a.y,a.z,a.w,b.x,b.y,b.z,b.w,
                                   c.x,c.y,c.z,c.w,d.x,d.y,d.z,d.w};
#pragma unroll
        for (int j = 0; j < 16; ++j) t[sl][c0 + j] = vals[j];
    }
    __syncthreads();
    const int sl2 = (lane & 31) * 2;         // 0..62 (s pair within tile)
    const int dh  = (lane >> 5) * 8;         // 0 or 8 (d-half within wave's 16)
#pragma unroll
    for (int j = 0; j < 8; ++j) {
        const int d = w * 16 + dh + j;
        const unsigned int lo = t[sl2][d], hi = t[sl2 + 1][d];
        const unsigned int pk = (lo & 0xFFFFu) | (hi << 16);
        *(unsigned int*)(vtb + ((size_t)bh * HD_ + d) * S_ + st * 64 + sl2) = pk;
    }
}

// ---------------------------------------------------------------------------
// bf16 GEMM body (128x128 tile): proven 2-buffer __syncthreads structure.
__device__ __forceinline__ void gemm_body(
    const __hip_bfloat16* __restrict__ A,
    const __hip_bfloat16* __restrict__ Bt,
    const float* __restrict__ bias,
    void* __restrict__ Cout, int mode,
    __hip_bfloat16 (*As)[128 * 32], __hip_bfloat16 (*Bs)[128 * 32],
    int bm, int bn)
{
    constexpr int K = 1024, N = 1024;
    const int tid = threadIdx.x;
    const int wid = tid >> 6, lane = tid & 63;
    const int wm = (wid >> 1) * 64, wn = (wid & 1) * 64;

    f32x4 acc[4][4] = {};

    const int srow = lane >> 2;          // 0..15 (row within 16-row chunk)
    const int scol = (lane & 3) * 8;     // elem col within 32-elem row

    auto stage = [&](int kt, int buf) {
#pragma unroll
        for (int i = 0; i < 2; ++i) {
            const int rb = wid * 32 + i * 16;
            gld_lds16(A  + (size_t)(bm + rb + srow) * K + kt * 32 + scol, (char*)As[buf] + rb * 64);
            gld_lds16(Bt + (size_t)(bn + rb + srow) * K + kt * 32 + scol, (char*)Bs[buf] + rb * 64);
        }
    };

    stage(0, 0);
    __syncthreads();

    for (int kt = 0; kt < K / 32; ++kt) {
        const int cur = kt & 1;
        if (kt < K / 32 - 1) stage(kt + 1, cur ^ 1);
        bfx8 af[4], bf[4];
#pragma unroll
        for (int m = 0; m < 4; ++m)
            af[m] = *(const bfx8*)((const char*)As[cur] + (wm + m * 16 + (lane & 15)) * 64 + (lane >> 4) * 16);
#pragma unroll
        for (int n = 0; n < 4; ++n)
            bf[n] = *(const bfx8*)((const char*)Bs[cur] + (wn + n * 16 + (lane & 15)) * 64 + (lane >> 4) * 16);
        __builtin_amdgcn_s_setprio(1);
#pragma unroll
        for (int m = 0; m < 4; ++m)
#pragma unroll
            for (int n = 0; n < 4; ++n)
                acc[m][n] = __builtin_amdgcn_mfma_f32_16x16x32_bf16(af[m], bf[n], acc[m][n], 0, 0, 0);
        __builtin_amdgcn_s_setprio(0);
        __syncthreads();
    }

#pragma unroll
    for (int m = 0; m < 4; ++m) {
        const int row0 = bm + wm + m * 16 + ((lane >> 4) << 2);
#pragma unroll
        for (int n = 0; n < 4; ++n) {
            const int col = bn + wn + n * 16 + (lane & 15);
            const float bv = bias[col];
#pragma unroll
            for (int r = 0; r < 4; ++r) {
                const int i = row0 + r;
                const float v = acc[m][n][r] + bv;
                if (mode == 2) {
                    ((float*)Cout)[(size_t)i * N + col] = v;
                } else {
                    const int b = i >> 11, s = i & 2047, h = col >> 6, d = col & 63;
                    ((__hip_bfloat16*)Cout)[(((size_t)b * H_ + h) * S_ + s) * HD_ + d] = __float2bfloat16(v);
                }
            }
        }
    }
}

// fused Q/K/V projections (3 blocks/CU)
__global__ __launch_bounds__(256, 3) void gemm_qkv(
    const __hip_bfloat16* __restrict__ xq, const __hip_bfloat16* __restrict__ xk,
    const __hip_bfloat16* __restrict__ xv,
    const __hip_bfloat16* __restrict__ Wqt, const __hip_bfloat16* __restrict__ Wkt,
    const __hip_bfloat16* __restrict__ Wvt,
    const float* __restrict__ bq, const float* __restrict__ bk, const float* __restrict__ bv,
    __hip_bfloat16* __restrict__ qb, __hip_bfloat16* __restrict__ kbuf,
    __hip_bfloat16* __restrict__ vnb)
{
    __shared__ __align__(16) __hip_bfloat16 As[2][128 * 32];
    __shared__ __align__(16) __hip_bfloat16 Bs[2][128 * 32];
    const int z = blockIdx.z;
    const __hip_bfloat16* A  = z == 0 ? xq : z == 1 ? xk : xv;
    const __hip_bfloat16* Bt = z == 0 ? Wqt : z == 1 ? Wkt : Wvt;
    const float* bias        = z == 0 ? bq : z == 1 ? bk : bv;
    void* out                = z == 0 ? (void*)qb : z == 1 ? (void*)kbuf : (void*)vnb;
    gemm_body(A, Bt, bias, out, 0, As, Bs, blockIdx.x * 128, blockIdx.y * 128);
}

// output projection: BM=128, BN=64 tile -> 512 blocks = 2/CU
__global__ __launch_bounds__(256, 2) void gemm_wo(
    const __hip_bfloat16* __restrict__ A, const __hip_bfloat16* __restrict__ Bt,
    const float* __restrict__ bias, float* __restrict__ Cout)
{
    constexpr int K = 1024, N = 1024;
    __shared__ __align__(16) __hip_bfloat16 As[2][128 * 32];
    __shared__ __align__(16) __hip_bfloat16 Bs[2][64 * 32];
    const int tid = threadIdx.x;
    const int wid = tid >> 6, lane = tid & 63;
    const int wm = (wid >> 1) * 64, wn = (wid & 1) * 32;
    const int bm = blockIdx.x * 128, bn = blockIdx.y * 64;

    f32x4 acc[4][2] = {};

    const int srow = lane >> 2;
    const int scol = (lane & 3) * 8;

    auto stage = [&](int kt, int buf) {
#pragma unroll
        for (int i = 0; i < 2; ++i) {
            const int rb = wid * 32 + i * 16;
            gld_lds16(A + (size_t)(bm + rb + srow) * K + kt * 32 + scol, (char*)As[buf] + rb * 64);
        }
        const int rbB = wid * 16;
        gld_lds16(Bt + (size_t)(bn + rbB + srow) * K + kt * 32 + scol, (char*)Bs[buf] + rbB * 64);
    };

    stage(0, 0);
    __syncthreads();

    for (int kt = 0; kt < K / 32; ++kt) {
        const int cur = kt & 1;
        if (kt < K / 32 - 1) stage(kt + 1, cur ^ 1);
        bfx8 af[4], bf[2];
#pragma unroll
        for (int m = 0; m < 4; ++m)
            af[m] = *(const bfx8*)((const char*)As[cur] + (wm + m * 16 + (lane & 15)) * 64 + (lane >> 4) * 16);
#pragma unroll
        for (int n = 0; n < 2; ++n)
            bf[n] = *(const bfx8*)((const char*)Bs[cur] + (wn + n * 16 + (lane & 15)) * 64 + (lane >> 4) * 16);
        __builtin_amdgcn_s_setprio(1);
#pragma unroll
        for (int m = 0; m < 4; ++m)
#pragma unroll
            for (int n = 0; n < 2; ++n)
                acc[m][n] = __builtin_amdgcn_mfma_f32_16x16x32_bf16(af[m], bf[n], acc[m][n], 0, 0, 0);
        __builtin_amdgcn_s_setprio(0);
        __syncthreads();
    }

#pragma unroll
    for (int m = 0; m < 4; ++m) {
        const int row0 = bm + wm + m * 16 + ((lane >> 4) << 2);
#pragma unroll
        for (int n = 0; n < 2; ++n) {
            const int col = bn + wn + n * 16 + (lane & 15);
            const float bv = bias[col];
#pragma unroll
            for (int r = 0; r < 4; ++r)
                Cout[(size_t)(row0 + r) * N + col] = acc[m][n][r] + bv;
        }
    }
}

// ---------------------------------------------------------------------------
// Fused attention (the proven 201us structure): 2-pass flash, 64 q-rows per
// block, 1024 blocks, 4 blocks/CU (TLP at 4/CU is load-bearing for the
// store-bound pass 2 — halving it cost +24us in R14). pass1 K ring-4
// prefetch-2 counted vmcnt; pass2 swapped QK^T + packed P-writes + nt f32x4
// attnw stores riding across iterations via vmcnt(4).
__global__ __launch_bounds__(256, 4) void attn_fused(
    const __hip_bfloat16* __restrict__ qb,   // [B,H,S,64]
    const __hip_bfloat16* __restrict__ kb,   // [B,H,S,64]
    const __hip_bfloat16* __restrict__ vt,   // [B,H,64,S]
    float* __restrict__ attnw,               // [B,H,S,S]
    __hip_bfloat16* __restrict__ aout)       // [B,S,H*64]
{
    __shared__ __align__(16) char lds_[40960];
    char* const ps_ = lds_ + 32768;          // 64 rows x 128B

    const int wg  = blockIdx.x;              // 0..1023
    const int lin = (wg & 7) * 128 + (wg >> 3);
    const int bh  = lin >> 5;                // b*16+h
    const int qt  = lin & 31;                // q tile 0..31 (64 rows each)

    const int tid = threadIdx.x, wid = tid >> 6, lane = tid & 63;
    const int qrow0 = qt * 64 + wid * 16;    // wave's first q row (s index)

    const char* kh = (const char*)(kb + (size_t)bh * S_ * HD_);   // head base
    const char* vh = (const char*)(vt + (size_t)bh * HD_ * S_);

    bfx8 qf[2];
#pragma unroll
    for (int kx = 0; kx < 2; ++kx)
        qf[kx] = *(const bfx8*)(qb + ((size_t)bh * S_ + qrow0 + (lane & 15)) * HD_
                                 + kx * 32 + (lane >> 4) * 8);

    const int sr = lane >> 3;   // row within 8-row staging chunk
    const int sc = lane & 7;    // 16B unit within 128B row

    auto stage_k = [&](int kt, char* dst) {
#pragma unroll
        for (int i = 0; i < 2; ++i) {
            const int rb = wid * 16 + i * 8;
            const int row = rb + sr;
            const int colb = (sc * 16) ^ ((row & 7) << 4);
            gld_lds16(kh + (size_t)(kt * 64 + row) * 128 + colb, dst + rb * 128);
        }
    };
    auto stage_v = [&](int kt, char* dst) {
#pragma unroll
        for (int i = 0; i < 2; ++i) {
            const int rb = wid * 16 + i * 8;
            const int row = rb + sr;
            const int colb = (sc * 16) ^ ((row & 7) << 4);
            gld_lds16(vh + ((size_t)row * S_ + kt * 64) * 2 + colb, dst + rb * 128);
        }
    };

    // ---------------- pass 1: denominators, K ring-4, prefetch depth 2 ------
    float lsum = 0.f;
    stage_k(0, lds_);
    stage_k(1, lds_ + 8192);
    for (int kt = 0; kt < 32; ++kt) {
        if (kt < 30) {
            stage_k(kt + 2, lds_ + ((kt + 2) & 3) * 8192);
            VWAIT(4);                       // loads(kt) retired; kt+1,kt+2 ride
        } else if (kt == 30) { VWAIT(2); } else { VWAIT(0); }
        __builtin_amdgcn_sched_barrier(0);
        __builtin_amdgcn_s_barrier();

        const char* kbase = lds_ + (kt & 3) * 8192;
        f32x4 c[4] = {};
#pragma unroll
        for (int kx = 0; kx < 2; ++kx) {
            bfx8 bfv[4];
#pragma unroll
            for (int cf = 0; cf < 4; ++cf) {
                const int row = cf * 16 + (lane & 15);
                bfv[cf] = *(const bfx8*)(kbase + row * 128
                                          + ((kx * 64 + (lane >> 4) * 16) ^ ((row & 7) << 4)));
            }
            __builtin_amdgcn_s_setprio(1);
#pragma unroll
            for (int cf = 0; cf < 4; ++cf)
                c[cf] = __builtin_amdgcn_mfma_f32_16x16x32_bf16(bfv[cf], qf[kx], c[cf], 0, 0, 0);
            __builtin_amdgcn_s_setprio(0);
        }
#pragma unroll
        for (int cf = 0; cf < 4; ++cf)
            lsum += exp2f(c[cf][0] * SC2_) + exp2f(c[cf][1] * SC2_)
                  + exp2f(c[cf][2] * SC2_) + exp2f(c[cf][3] * SC2_);
    }
    float llog;
    {
        float s = lsum;
        s += __shfl_xor(s, 16);
        s += __shfl_xor(s, 32);
        llog = -__log2f(s);
    }

    // ---------------- pass 2: weights + PV ----------------
    f32x4 o[4] = {};
    stage_k(0, lds_);
    stage_v(0, lds_ + 16384);
    VWAIT(0);
    __builtin_amdgcn_s_barrier();
    for (int kt = 0; kt < 32; ++kt) {
        const int cur = kt & 1;
        const char* ksb = lds_ + cur * 8192;
        const char* vsb = lds_ + 16384 + cur * 8192;

        if (kt < 31) {
            stage_k(kt + 1, lds_ + (cur ^ 1) * 8192);
            stage_v(kt + 1, lds_ + 16384 + (cur ^ 1) * 8192);
        }

        f32x4 c[4] = {};
#pragma unroll
        for (int kx = 0; kx < 2; ++kx) {
            bfx8 bfv[4];
#pragma unroll
            for (int cf = 0; cf < 4; ++cf) {
                const int row = cf * 16 + (lane & 15);
                bfv[cf] = *(const bfx8*)(ksb + row * 128
                                          + ((kx * 64 + (lane >> 4) * 16) ^ ((row & 7) << 4)));
            }
            __builtin_amdgcn_s_setprio(1);
#pragma unroll
            for (int cf = 0; cf < 4; ++cf)
                c[cf] = __builtin_amdgcn_mfma_f32_16x16x32_bf16(bfv[cf], qf[kx], c[cf], 0, 0, 0);
            __builtin_amdgcn_s_setprio(0);
        }

        {
            const int q = lane & 15;
            char* const prow_base = ps_ + (wid * 16 + q) * 128;
            const int swz = (q & 7) << 4;
#pragma unroll
            for (int cf = 0; cf < 4; ++cf) {
                const int k0b = (cf * 16 + (lane >> 4) * 4) * 2;
                ushort4 pk;
                __hip_bfloat16 bb;
                bb = __float2bfloat16(exp2f(fmaf(c[cf][0], SC2_, llog))); pk.x = *(unsigned short*)&bb;
                bb = __float2bfloat16(exp2f(fmaf(c[cf][1], SC2_, llog))); pk.y = *(unsigned short*)&bb;
                bb = __float2bfloat16(exp2f(fmaf(c[cf][2], SC2_, llog))); pk.z = *(unsigned short*)&bb;
                bb = __float2bfloat16(exp2f(fmaf(c[cf][3], SC2_, llog))); pk.w = *(unsigned short*)&bb;
                *(ushort4*)(prow_base + (k0b ^ swz)) = pk;
            }
        }

#pragma unroll
        for (int rr = 0; rr < 4; ++rr) {
            const int p = wid * 16 + rr * 4 + (lane >> 4);
            const uint2 u = *(const uint2*)(ps_ + p * 128
                                            + (((lane & 15) * 8) ^ ((p & 7) << 4)));
            f32x4 f;
            f[0] = __uint_as_float(u.x << 16);
            f[1] = __uint_as_float(u.x & 0xFFFF0000u);
            f[2] = __uint_as_float(u.y << 16);
            f[3] = __uint_as_float(u.y & 0xFFFF0000u);
            __builtin_nontemporal_store(f,
                (f32x4*)(attnw + ((size_t)bh * S_ + qt * 64 + p) * S_ + kt * 64 + (lane & 15) * 4));
        }

#pragma unroll
        for (int kx = 0; kx < 2; ++kx) {
            bfx8 pf, vf[4];
            {
                const int prow = wid * 16 + (lane & 15);
                pf = *(const bfx8*)(ps_ + prow * 128
                                     + ((kx * 64 + (lane >> 4) * 16) ^ ((prow & 7) << 4)));
            }
#pragma unroll
            for (int df = 0; df < 4; ++df) {
                const int vrow = df * 16 + (lane & 15);
                vf[df] = *(const bfx8*)(vsb + vrow * 128
                                         + ((kx * 64 + (lane >> 4) * 16) ^ ((vrow & 7) << 4)));
            }
            __builtin_amdgcn_s_setprio(1);
#pragma unroll
            for (int df = 0; df < 4; ++df)
                o[df] = __builtin_amdgcn_mfma_f32_16x16x32_bf16(pf, vf[df], o[df], 0, 0, 0);
            __builtin_amdgcn_s_setprio(0);
        }

        if (kt < 31) {
            VWAIT(4);                              // stage loads done; stores ride on
            __builtin_amdgcn_sched_barrier(0);
            __builtin_amdgcn_s_barrier();
        }
    }

    const int b = bh >> 4, h = bh & 15;
#pragma unroll
    for (int r = 0; r < 4; ++r) {
        const int s = qrow0 + ((lane >> 4) << 2) + r;
#pragma unroll
        for (int df = 0; df < 4; ++df) {
            const int d = df * 16 + (lane & 15);
            aout[((size_t)b * S_ + s) * D_ + h * HD_ + d] = __float2bfloat16(o[df][r]);
        }
    }
}

// ---------------------------------------------------------------------------
extern "C" void kernel_launch(void* const* d_in, const int* in_sizes, int n_in,
                              void* d_out, int out_size, void* d_ws, size_t ws_size,
                              hipStream_t stream)
{
    (void)in_sizes; (void)n_in; (void)out_size; (void)ws_size;
    const float* query = (const float*)d_in[0];
    const float* key_  = (const float*)d_in[1];
    const float* value = (const float*)d_in[2];
    const float* Wq = (const float*)d_in[3];
    const float* bq = (const float*)d_in[4];
    const float* Wk = (const float*)d_in[5];
    const float* bk = (const float*)d_in[6];
    const float* Wv = (const float*)d_in[7];
    const float* bv = (const float*)d_in[8];
    const float* Wo = (const float*)d_in[9];
    const float* bo = (const float*)d_in[10];

    char* ws = (char*)d_ws;
    const size_t MB = 1u << 20;
    __hip_bfloat16* xq   = (__hip_bfloat16*)(ws + 0 * MB);
    __hip_bfloat16* xk   = (__hip_bfloat16*)(ws + 8 * MB);
    __hip_bfloat16* xv   = (__hip_bfloat16*)(ws + 16 * MB);
    __hip_bfloat16* Wqt  = (__hip_bfloat16*)(ws + 24 * MB);
    __hip_bfloat16* Wkt  = (__hip_bfloat16*)(ws + 26 * MB);
    __hip_bfloat16* Wvt  = (__hip_bfloat16*)(ws + 28 * MB);
    __hip_bfloat16* Wot  = (__hip_bfloat16*)(ws + 30 * MB);
    __hip_bfloat16* qb   = (__hip_bfloat16*)(ws + 32 * MB);
    __hip_bfloat16* kbuf = (__hip_bfloat16*)(ws + 40 * MB);
    __hip_bfloat16* vtb  = (__hip_bfloat16*)(ws + 48 * MB);
    // vnb (natural-layout V) aliases aout: vnb is dead after transpose_v,
    // and attn_fused (which writes aout) runs strictly after it.
    __hip_bfloat16* vnb  = (__hip_bfloat16*)(ws + 56 * MB);
    __hip_bfloat16* aout = (__hip_bfloat16*)(ws + 56 * MB);

    float* outp  = (float*)d_out;
    float* attnw = outp + (size_t)B_ * S_ * D_;

    prep<<<dim3(16384), 256, 0, stream>>>(query, key_, value, xq, xk, xv,
                                          Wq, Wk, Wv, Wo, Wqt, Wkt, Wvt, Wot);
    gemm_qkv<<<dim3(32, 8, 3), 256, 0, stream>>>(xq, xk, xv, Wqt, Wkt, Wvt, bq, bk, bv, qb, kbuf, vnb);
    transpose_v<<<dim3(32, 32), 256, 0, stream>>>(vnb, vtb);
    attn_fused<<<dim3(1024), 256, 0, stream>>>(qb, kbuf, vtb, attnw, aout);
    gemm_wo<<<dim3(32, 16), 256, 0, stream>>>(aout, Wot, bo, outp);
}